// Round 11
// baseline (73.026 us; speedup 1.0000x reference)
//
#include <hip/hip_runtime.h>

#define THREADS 256
#define CPZ 4                  // puzzles per chunk
#define CC (CPZ * 81)          // 324 cells
#define CW (CC * 9)            // 2916 words per chunk buffer
#define CF4 (CW / 4)           // 729 float4
#define MAXG 1536              // 6 blocks/CU x 256 CU

typedef float f4 __attribute__((ext_vector_type(4)));
typedef float f2 __attribute__((ext_vector_type(2)));
typedef int   i2 __attribute__((ext_vector_type(2)));
typedef __fp16 h2 __attribute__((ext_vector_type(2)));
typedef unsigned int u32;
typedef u32 u2 __attribute__((ext_vector_type(2)));

static __device__ __forceinline__ u32 pkrtz(float a, float b) {
  h2 v = __builtin_amdgcn_cvt_pkrtz(a, b);     // v_cvt_pkrtz_f16_f32
  return __builtin_bit_cast(u32, v);
}

__global__ __launch_bounds__(THREADS) void sudoku_main(
    const float* __restrict__ logits,
    const int*   __restrict__ targets,
    const int*   __restrict__ puzzles,
    float* __restrict__ partial,       // [5][grid]
    int B, long nchunk, int grid)
{
  __shared__ float buf[2][CW];         // double-buffered chunk (23.3 KB)
  __shared__ float sred[4][5];

  const int tid  = threadIdx.x;
  const int wv   = tid >> 6, lane = tid & 63;
  const long totalCells = (long)B * 81;
  const long totF4      = totalCells * 9 / 4;
  const bool stager  = tid < 243;

  float a_focal=0.f, a_ent=0.f, a_msk=0.f, a_uniq=0.f, a_sq=0.f;

  // ---- prologue: stage chunk c0 into buf[0]; load its ints ----
  const long c0 = blockIdx.x;
  if (stager) {
    const f4* src = (const f4*)logits;
    const long b4 = c0 * CF4;
#pragma unroll
    for (int r = 0; r < 3; ++r) {
      long idx = b4 + r * 243 + tid;
      if (idx < totF4) ((f4*)buf[0])[r * 243 + tid] = src[idx];
    }
  }
  bool vA = false; i2 tgc{}, pzc{};
  {
    const long cell0 = c0 * CC + 2 * tid;
    vA = (tid < 162) && (cell0 + 1 < totalCells);
    if (vA) { tgc = *(const i2*)(targets + cell0); pzc = *(const i2*)(puzzles + cell0); }
  }

  int it = 0;
  for (long c = c0; c < nchunk; c += grid, ++it) {
    float* X = buf[it & 1];
    float* Y = buf[(it & 1) ^ 1];
    __syncthreads();                   // bar1: X staged & visible; phaseC(c-1) done

    // ---- issue next-chunk loads into registers (in flight through computeA) ----
    const long cn = c + grid;
    f4 r0{}, r1{}, r2{};
    const bool vS = stager && (cn < nchunk);
    if (vS) {
      const f4* src = (const f4*)logits;
      const long b4 = cn * CF4;
      long i0 = b4 + tid, i1 = b4 + 243 + tid, ii2 = b4 + 486 + tid;
      if (i0  < totF4) r0 = src[i0];
      if (i1  < totF4) r1 = src[i1];
      if (ii2 < totF4) r2 = src[ii2];
    }
    bool vAn = false; i2 tgn{}, pzn{};
    if (cn < nchunk) {
      const long cell0n = cn * CC + 2 * tid;
      vAn = (tid < 162) && (cell0n + 1 < totalCells);
      if (vAn) { tgn = *(const i2*)(targets + cell0n); pzn = *(const i2*)(puzzles + cell0n); }
    }

    // ---- computeA(c): 162 lanes x 2 cells, register softmax, probs in place ----
    if (vA) {
      f2 v[9];
      const f2* xp = (const f2*)(X + 18 * tid);    // byte 72t: 8B-aligned
#pragma unroll
      for (int q = 0; q < 9; ++q) v[q] = xp[q];

      u32 q5[2][5];
#pragma unroll
      for (int k = 0; k < 2; ++k) {
        float l[9];
#pragma unroll
        for (int i = 0; i < 9; ++i) { const int w = 9 * k + i; l[i] = v[w >> 1][w & 1]; }
        int tg = ((k == 0) ? tgc[0] : tgc[1]) - 1; tg = tg < 0 ? 0 : (tg > 8 ? 8 : tg);
        const int pz = (k == 0) ? pzc[0] : pzc[1];

        float t1 = l[0], t2 = -3.0e38f;            // branchless top-2 of logits
#pragma unroll
        for (int i = 1; i < 9; ++i) {
          float hi = fmaxf(t1, l[i]);
          float lo = fminf(t1, l[i]);
          t1 = hi; t2 = fmaxf(t2, lo);
        }
        float e[9], ssum = 0.f, lsum = 0.f, ltg = l[0];
#pragma unroll
        for (int i = 0; i < 9; ++i) {
          float x  = l[i] - t1;
          float ei = __expf(x);
          e[i] = ei; ssum += ei;
          lsum = fmaf(ei, x, lsum);
          if (i > 0) ltg = (tg == i) ? l[i] : ltg;
        }
        float inv_s = __builtin_amdgcn_rcpf(ssum);
        float logs  = __logf(ssum);
        float lpt   = (ltg - t1) - logs;
        float pt    = __expf(lpt);
        float om    = 1.f - pt;
        float focal = om * om * (-lpt);
        float ent   = logs - lsum * inv_s;
        float gap   = (1.f - __expf(t2 - t1)) * inv_s;
        float uq    = fmaxf(0.f, 1.f - gap);
        float mk    = (pz == 0) ? 1.f : 0.f;
        a_focal += focal * mk;
        a_ent   += ent * mk;
        a_msk   += mk;
        a_uniq  += uq;                             // uniqueness is unmasked
        float pm = inv_s * mk;
        q5[k][0] = pkrtz(e[0]*pm, e[1]*pm);
        q5[k][1] = pkrtz(e[2]*pm, e[3]*pm);
        q5[k][2] = pkrtz(e[4]*pm, e[5]*pm);
        q5[k][3] = pkrtz(e[6]*pm, e[7]*pm);
        q5[k][4] = pkrtz(e[8]*pm, 0.f);
      }
      // probs at words 9cc..9cc+4 (cc = 2t, 2t+1), alignment-safe stores
      u32* wp = (u32*)(X + 18 * tid);
      { u2 a; a[0]=q5[0][0]; a[1]=q5[0][1]; *(u2*)(wp + 0) = a; }
      { u2 a; a[0]=q5[0][2]; a[1]=q5[0][3]; *(u2*)(wp + 2) = a; }
      wp[4] = q5[0][4];
      wp[9] = q5[1][0];
      { u2 a; a[0]=q5[1][1]; a[1]=q5[1][2]; *(u2*)(wp + 10) = a; }
      { u2 a; a[0]=q5[1][3]; a[1]=q5[1][4]; *(u2*)(wp + 12) = a; }
    }

    // ---- stage-write next chunk (vmcnt wait lands here, after computeA) ----
    if (vS) {
      f4* yp = (f4*)Y;
      yp[tid] = r0; yp[243 + tid] = r1; yp[486 + tid] = r2;
    }
    __syncthreads();                   // bar2: probs(c) + stage(c+1) visible

    // ---- phaseC(c): one rotating wave, 20 lanes = (4 puzzles x 5 pairs) ----
    if (wv == (it & 3) && lane < CPZ * 5) {
      const int pzl = lane / 5, pr = lane % 5;
      if (c * CPZ + pzl < (long)B) {
        const u32* cb = (const u32*)X;
        h2 hz; hz[0] = (__fp16)0.f; hz[1] = (__fp16)0.f;
        h2 rs[9], cs[9], bs[9];
#pragma unroll
        for (int u = 0; u < 9; ++u) { rs[u] = hz; cs[u] = hz; bs[u] = hz; }
        const int base = pzl * 729 + pr;
#pragma unroll
        for (int j = 0; j < 81; ++j) {
          h2 pv = __builtin_bit_cast(h2, cb[base + 9 * j]);
          rs[j / 9]                      += pv;
          cs[j % 9]                      += pv;
          bs[(j / 27) * 3 + (j % 9) / 3] += pv;
        }
        const float hiw = (pr == 4) ? 0.f : 1.f;   // pad class excluded
        float sq = 0.f;
#pragma unroll
        for (int u = 0; u < 9; ++u) {
          float x;
          x = (float)rs[u][0] - 1.f; sq = fmaf(x, x, sq);
          x = (float)cs[u][0] - 1.f; sq = fmaf(x, x, sq);
          x = (float)bs[u][0] - 1.f; sq = fmaf(x, x, sq);
          x = (float)rs[u][1] - 1.f; sq = fmaf(hiw * x, x, sq);
          x = (float)cs[u][1] - 1.f; sq = fmaf(hiw * x, x, sq);
          x = (float)bs[u][1] - 1.f; sq = fmaf(hiw * x, x, sq);
        }
        a_sq += sq;
      }
    }

    vA = vAn; tgc = tgn; pzc = pzn;
  }

  // ---- wave + block reduction, transposed partial store (no atomics) ----
#pragma unroll
  for (int off = 32; off > 0; off >>= 1) {
    a_focal += __shfl_down(a_focal, off);
    a_ent   += __shfl_down(a_ent,   off);
    a_msk   += __shfl_down(a_msk,   off);
    a_uniq  += __shfl_down(a_uniq,  off);
    a_sq    += __shfl_down(a_sq,    off);
  }
  if (lane == 0) {
    sred[wv][0] = a_focal; sred[wv][1] = a_ent; sred[wv][2] = a_msk;
    sred[wv][3] = a_uniq;  sred[wv][4] = a_sq;
  }
  __syncthreads();
  if (tid < 5) {
    float v = sred[0][tid] + sred[1][tid] + sred[2][tid] + sred[3][tid];
    partial[(size_t)tid * grid + blockIdx.x] = v;
  }
}

__global__ __launch_bounds__(1024) void sudoku_finalize(
    const float* __restrict__ partial, float* __restrict__ out,
    int nblk, float invBG)
{
  __shared__ float sb[16][5];
  const int tid = threadIdx.x;
  float s[5] = {0.f, 0.f, 0.f, 0.f, 0.f};
  for (int b = tid; b < nblk; b += 1024) {
#pragma unroll
    for (int u = 0; u < 5; ++u) s[u] += partial[(size_t)u * nblk + b];   // coalesced
  }
#pragma unroll
  for (int off = 32; off > 0; off >>= 1)
#pragma unroll
    for (int u = 0; u < 5; ++u) s[u] += __shfl_down(s[u], off);
  const int wv = tid >> 6, lane = tid & 63;
  if (lane == 0) {
#pragma unroll
    for (int u = 0; u < 5; ++u) sb[wv][u] = s[u];
  }
  __syncthreads();
  if (tid == 0) {
    float focal = 0.f, ent = 0.f, msum = 0.f, uniq = 0.f, sq = 0.f;
#pragma unroll
    for (int w = 0; w < 16; ++w) {
      focal += sb[w][0]; ent += sb[w][1]; msum += sb[w][2];
      uniq  += sb[w][3]; sq  += sb[w][4];
    }
    float inv_m = 1.f / (msum + 1e-8f);
    float ce    = focal * inv_m;
    float entl  = 0.1f * ent * inv_m;
    float uql   = 0.1f * uniq * invBG;
    float rcb   = sq * invBG;        // row+col+box means share denominator B*81
    float constraint = (rcb + entl + uql) * 0.2f;
    out[0] = ce + 0.5f * constraint;
  }
}

extern "C" void kernel_launch(void* const* d_in, const int* in_sizes, int n_in,
                              void* d_out, int out_size, void* d_ws, size_t ws_size,
                              hipStream_t stream)
{
  (void)n_in; (void)out_size; (void)ws_size;
  const float* logits  = (const float*)d_in[0];
  const int*   targets = (const int*)d_in[1];
  const int*   puzzles = (const int*)d_in[2];
  float* out = (float*)d_out;
  float* partial = (float*)d_ws;

  const int B = in_sizes[0] / 729;                   // B*9*9*9 logits
  const long nchunk = ((long)B + CPZ - 1) / CPZ;     // 16384 @ B=65536
  const int grid = (int)(nchunk < MAXG ? nchunk : MAXG);

  sudoku_main<<<grid, THREADS, 0, stream>>>(logits, targets, puzzles, partial,
                                            B, nchunk, grid);

  const float invBG = 1.f / ((float)B * 81.f);
  sudoku_finalize<<<1, 1024, 0, stream>>>(partial, out, grid, invBG);
}